// Round 2
// 434.015 us; speedup vs baseline: 1.0608x; 1.0608x over previous
//
#include <hip/hip_runtime.h>

// B=64, C=512, H=W=28, NL=4. Multi-launch (graph-capture safe), 9 dispatches.
// Cell algebra: g_h2 (second cell's hh path) == hh-path(ht_new[0]) == row 0 of the
// NEXT layer's g_hpre, so each cell launch computes g_hpre[b] = MLP_hh(ht_new[b])
// at its tail: no serial block-0 tail, and the hh matvec is off the critical path
// of the next layer's cell. Layer 0 reads g_h0 (separate buffer; avoids the row-0
// read/write race).

#define HW 784
#define F4 196        // float4 per 28x28 plane
#define CC 512
#define BB 64
#define TS 31         // LDS tile row stride (30x30 tile, +1 pad)

__device__ __forceinline__ float sigm(float x) { return 1.f / (1.f + __expf(-x)); }

// ---- pool (8192 blocks x 4 planes) + g_h0 (blocks 0-5) + ct zero (blocks 6-133) ----
__global__ void __launch_bounds__(256) pool_init_kernel(
        const float* __restrict__ x, float* __restrict__ seq,
        float* __restrict__ ct, float* __restrict__ g_h0,
        const float* __restrict__ w_hh2, const float* __restrict__ b_hh1,
        const float* __restrict__ b_hh2) {
    int blk = blockIdx.x, t = threadIdx.x;
    int wave = t >> 6, lane = t & 63;
    int p = blk * 4 + wave;
    const float4* b4 = (const float4*)(x + (size_t)p * HW);
    float s = 0.f;
    for (int j = lane; j < F4; j += 64) {
        float4 v = b4[j];
        s += v.x + v.y + v.z + v.w;
    }
    #pragma unroll
    for (int off = 32; off > 0; off >>= 1) s += __shfl_down(s, off, 64);
    if (lane == 0) seq[p] = s * (1.f / 784.f);

    if (blk < 6) {          // g_h0 = W_hh2 . relu(b_hh1) + b_hh2 (layer-0 hh path, ht=0)
        int o = blk * 256 + t;
        const float4* wv4 = (const float4*)(w_hh2 + o * 32);
        float acc = b_hh2[o];
        #pragma unroll
        for (int j = 0; j < 8; ++j) {
            float4 w = wv4[j];
            acc += fmaxf(b_hh1[4*j+0], 0.f) * w.x + fmaxf(b_hh1[4*j+1], 0.f) * w.y
                 + fmaxf(b_hh1[4*j+2], 0.f) * w.z + fmaxf(b_hh1[4*j+3], 0.f) * w.w;
        }
        g_h0[o] = acc;
    } else if (blk < 134) { // zero ct (64*512 = 32768 floats)
        ct[(blk - 6) * 256 + t] = 0.f;
    }
}

// ---- one cell per block (b = batch), 512 threads = 8 waves ----
__global__ void __launch_bounds__(512) cell_kernel(
        const float* __restrict__ seq,
        const float* __restrict__ w_ih1, const float* __restrict__ b_ih1,
        const float* __restrict__ w_ih2, const float* __restrict__ b_ih2,
        const float* __restrict__ w_hh1, const float* __restrict__ b_hh1,
        const float* __restrict__ w_hh2, const float* __restrict__ b_hh2,
        float* __restrict__ G_i, float* __restrict__ ct,
        float* __restrict__ g_hpre, const float* __restrict__ g_h0,
        int layer) {
    __shared__ __align__(16) float s_in[CC];
    __shared__ float s_hid[32];
    __shared__ float s_g[1536];
    const int b = blockIdx.x, t = threadIdx.x;

    for (int k = t; k < CC; k += 512) s_in[k] = seq[b * CC + k];
    __syncthreads();

    // A-ih: 32 outputs x 16 lanes; each lane 8 float4 MACs over its 32-float slice
    {
        int o = t >> 4, q = t & 15;
        const float4* wv4 = (const float4*)(w_ih1 + o * CC) + q * 8;
        const float4* in4 = (const float4*)s_in + q * 8;
        float acc = 0.f;
        #pragma unroll
        for (int j = 0; j < 8; ++j) {
            float4 w = wv4[j], xv = in4[j];
            acc += xv.x*w.x + xv.y*w.y + xv.z*w.z + xv.w*w.w;
        }
        acc += __shfl_down(acc, 8, 64);
        acc += __shfl_down(acc, 4, 64);
        acc += __shfl_down(acc, 2, 64);
        acc += __shfl_down(acc, 1, 64);
        if (q == 0) s_hid[o] = fmaxf(acc + b_ih1[o], 0.f);
    }
    __syncthreads();

    // B: G_i[b,o] and s_g = G_i + g_h(prev ht). 3 outputs/thread.
    const float* ghsrc = (layer == 0) ? g_h0 : (g_hpre + (size_t)b * 1536);
    for (int o = t; o < 1536; o += 512) {
        const float4* wv4 = (const float4*)(w_ih2 + o * 32);
        float acc = 0.f;
        #pragma unroll
        for (int j = 0; j < 8; ++j) {
            float4 w = wv4[j];
            acc += s_hid[4*j]*w.x + s_hid[4*j+1]*w.y + s_hid[4*j+2]*w.z + s_hid[4*j+3]*w.w;
        }
        float gi = acc + b_ih2[o];
        G_i[b * 1536 + o] = gi;
        s_g[o] = gi + ghsrc[o];
    }
    __syncthreads();

    // C: gates -> ct, h (h into s_in)
    for (int c = t; c < CC; c += 512) {
        float nc = sigm(s_g[CC + c]) * ct[b * CC + c] + sigm(s_g[c]) * tanhf(s_g[2 * CC + c]);
        ct[b * CC + c] = nc;
        s_in[c] = sigm(nc);
    }
    __syncthreads();

    // A-hh on the new h row
    {
        int o = t >> 4, q = t & 15;
        const float4* wv4 = (const float4*)(w_hh1 + o * CC) + q * 8;
        const float4* in4 = (const float4*)s_in + q * 8;
        float acc = 0.f;
        #pragma unroll
        for (int j = 0; j < 8; ++j) {
            float4 w = wv4[j], xv = in4[j];
            acc += xv.x*w.x + xv.y*w.y + xv.z*w.z + xv.w*w.w;
        }
        acc += __shfl_down(acc, 8, 64);
        acc += __shfl_down(acc, 4, 64);
        acc += __shfl_down(acc, 2, 64);
        acc += __shfl_down(acc, 1, 64);
        if (q == 0) s_hid[o] = fmaxf(acc + b_hh1[o], 0.f);
    }
    __syncthreads();

    // B-hh -> g_hpre[b] (row 0 doubles as this layer's g_h2 for the update)
    for (int o = t; o < 1536; o += 512) {
        const float4* wv4 = (const float4*)(w_hh2 + o * 32);
        float acc = 0.f;
        #pragma unroll
        for (int j = 0; j < 8; ++j) {
            float4 w = wv4[j];
            acc += s_hid[4*j]*w.x + s_hid[4*j+1]*w.y + s_hid[4*j+2]*w.z + s_hid[4*j+3]*w.w;
        }
        g_hpre[(size_t)b * 1536 + o] = acc + b_hh2[o];
    }
}

// ---- y = x*(1+oh) + dw3x3(x); fused mean(y) -> seq_next. One block per plane ----
__global__ void __launch_bounds__(256) update_kernel(
        const float* __restrict__ x, float* __restrict__ y,
        const float* __restrict__ G_i, const float* __restrict__ g_hrow,
        const float* __restrict__ ct0, const float* __restrict__ dwk,
        float* __restrict__ seq_next) {
    __shared__ float tile[30 * TS];
    __shared__ float s_w[9];
    __shared__ float s_oh;
    __shared__ float s_part[256];
    int p = blockIdx.x;
    int b = p >> 9, c = p & 511;
    int t = threadIdx.x;  // 256 threads, 196 own one float4 each

    // zero the halo border (rows 0/29 cols 0..29; cols 0/29 rows 1..28)
    if (t < 30) tile[t] = 0.f;
    else if (t < 60) tile[29 * TS + (t - 30)] = 0.f;
    else if (t < 88) tile[(t - 59) * TS] = 0.f;
    else if (t < 116) tile[(t - 87) * TS + 29] = 0.f;
    if (t < 9) s_w[t] = dwk[c * 9 + t];
    if (t == 255) {
        const float* g = G_i + b * 1536;
        float ig = g[c] + g_hrow[c];
        float fg = g[CC + c] + g_hrow[CC + c];
        float cg = g[2 * CC + c] + g_hrow[2 * CC + c];
        float nc = sigm(fg) * ct0[c] + sigm(ig) * tanhf(cg);
        s_oh = sigm(nc);
    }

    int py = t / 7, px4 = t - py * 7;  // t<196: output row, float4 col
    if (t < F4) {
        float4 v = ((const float4*)(x + (size_t)p * HW))[t];
        float* dst = &tile[(py + 1) * TS + px4 * 4 + 1];
        dst[0] = v.x; dst[1] = v.y; dst[2] = v.z; dst[3] = v.w;
    }
    __syncthreads();

    float sum = 0.f;
    if (t < F4) {
        float oh1 = 1.f + s_oh;
        float w0 = s_w[0], w1 = s_w[1], w2 = s_w[2], w3 = s_w[3], w4 = s_w[4];
        float w5 = s_w[5], w6 = s_w[6], w7 = s_w[7], w8 = s_w[8];
        const float* r0 = &tile[py * TS + px4 * 4];
        const float* r1 = r0 + TS;
        const float* r2 = r0 + 2 * TS;
        float a0 = r0[0], a1 = r0[1], a2 = r0[2], a3 = r0[3], a4 = r0[4], a5 = r0[5];
        float b0 = r1[0], b1 = r1[1], b2 = r1[2], b3 = r1[3], b4 = r1[4], b5 = r1[5];
        float c0 = r2[0], c1 = r2[1], c2 = r2[2], c3 = r2[3], c4 = r2[4], c5 = r2[5];
        float y0 = b1 * oh1 + a0 * w0 + a1 * w1 + a2 * w2 + b0 * w3 + b1 * w4 + b2 * w5 + c0 * w6 + c1 * w7 + c2 * w8;
        float y1 = b2 * oh1 + a1 * w0 + a2 * w1 + a3 * w2 + b1 * w3 + b2 * w4 + b3 * w5 + c1 * w6 + c2 * w7 + c3 * w8;
        float y2 = b3 * oh1 + a2 * w0 + a3 * w1 + a4 * w2 + b2 * w3 + b3 * w4 + b4 * w5 + c2 * w6 + c3 * w7 + c4 * w8;
        float y3 = b4 * oh1 + a3 * w0 + a4 * w1 + a5 * w2 + b3 * w3 + b4 * w4 + b5 * w5 + c3 * w6 + c4 * w7 + c5 * w8;
        ((float4*)(y + (size_t)p * HW))[t] = make_float4(y0, y1, y2, y3);
        sum = y0 + y1 + y2 + y3;
    }
    s_part[t] = sum;
    __syncthreads();
    if (t < 64) {
        float s = s_part[t] + s_part[t + 64] + s_part[t + 128] + s_part[t + 192];
        for (int off = 32; off > 0; off >>= 1) s += __shfl_down(s, off, 64);
        if (t == 0) seq_next[p] = s * (1.f / 784.f);
    }
}

extern "C" void kernel_launch(void* const* d_in, const int* in_sizes, int n_in,
                              void* d_out, int out_size, void* d_ws, size_t ws_size,
                              hipStream_t stream) {
    const float* x_in  = (const float*)d_in[0];
    const float* w_ih1 = (const float*)d_in[1];
    const float* b_ih1 = (const float*)d_in[2];
    const float* w_ih2 = (const float*)d_in[3];
    const float* b_ih2 = (const float*)d_in[4];
    const float* w_hh1 = (const float*)d_in[5];
    const float* b_hh1 = (const float*)d_in[6];
    const float* w_hh2 = (const float*)d_in[7];
    const float* b_hh2 = (const float*)d_in[8];
    const float* dwk   = (const float*)d_in[9];
    float* out = (float*)d_out;
    char* ws = (char*)d_ws;

    float* seq    = (float*)(ws + 0);         // 64*512  = 131072 B
    float* G_i    = (float*)(ws + 131072);    // 64*1536 = 393216 B
    float* ct     = (float*)(ws + 524288);    // 64*512  = 131072 B
    float* g_hpre = (float*)(ws + 655360);    // 64*1536 = 393216 B (row 0 = g_h2)
    float* g_h0   = (float*)(ws + 1048576);   // 1536    = 6144 B (layer-0 hh path)

    pool_init_kernel<<<8192, 256, 0, stream>>>(x_in, seq, ct, g_h0, w_hh2, b_hh1, b_hh2);

    for (int layer = 0; layer < 4; layer++) {
        const float* xcur = (layer == 0) ? x_in : out;
        cell_kernel<<<BB, 512, 0, stream>>>(seq, w_ih1, b_ih1, w_ih2, b_ih2,
                                            w_hh1, b_hh1, w_hh2, b_hh2,
                                            G_i, ct, g_hpre, g_h0, layer);
        update_kernel<<<32768, 256, 0, stream>>>(xcur, out, G_i, g_hpre, ct, dwk, seq);
    }
}

// Round 3
// 374.886 us; speedup vs baseline: 1.2282x; 1.1577x over previous
//
#include <hip/hip_runtime.h>

// B=64, C=512, H=W=28, NL=4, fp32. Key algebra: per plane the layer update is
// LINEAR: x_{k+1} = (1+oh_k) x_k + K x_k (K = zero-padded depthwise 3x3).
// => x_4 = sum_{j=0..4} e_j K^j x_0, e = esp(1+oh_0..3) per plane.
// mean(x_k) = sum_j c_j^{(k)} mu_j with mu_j = <x_0, (K^T)^j 1>/784 (j=0..3),
// so the cells never need the spatial intermediates. 7 dispatches:
// wj (W_j images) -> stats (mu) -> cell x4 (coef evolution + LSTM state) -> mega.

#define HW 784
#define F4 196
#define CC 512
#define BB 64
#define NP 32768
#define TS 31

__device__ __forceinline__ float sigm(float x) { return 1.f / (1.f + __expf(-x)); }

// 3x3 stencil on a 30x31 padded tile: out row py, float4 col px4.
#define STENCIL(src, py, px4, w0,w1,w2,w3,w4,w5,w6,w7,w8, y0,y1,y2,y3) do { \
    const float* r0 = &(src)[(py) * TS + (px4) * 4]; \
    const float* r1 = r0 + TS; \
    const float* r2 = r0 + 2 * TS; \
    float a0=r0[0],a1=r0[1],a2=r0[2],a3=r0[3],a4=r0[4],a5=r0[5]; \
    float b0=r1[0],b1=r1[1],b2=r1[2],b3=r1[3],b4=r1[4],b5=r1[5]; \
    float c0=r2[0],c1=r2[1],c2=r2[2],c3=r2[3],c4=r2[4],c5=r2[5]; \
    y0 = a0*w0+a1*w1+a2*w2 + b0*w3+b1*w4+b2*w5 + c0*w6+c1*w7+c2*w8; \
    y1 = a1*w0+a2*w1+a3*w2 + b1*w3+b2*w4+b3*w5 + c1*w6+c2*w7+c3*w8; \
    y2 = a2*w0+a3*w1+a4*w2 + b2*w3+b3*w4+b4*w5 + c2*w6+c3*w7+c4*w8; \
    y3 = a3*w0+a4*w1+a5*w2 + b3*w3+b4*w4+b5*w5 + c3*w6+c4*w7+c5*w8; \
} while (0)

#define ZERO_HALO(tile) do { \
    if (t < 30) (tile)[t] = 0.f; \
    else if (t < 60) (tile)[29 * TS + (t - 30)] = 0.f; \
    else if (t < 88) (tile)[(t - 59) * TS] = 0.f; \
    else if (t < 116) (tile)[(t - 87) * TS + 29] = 0.f; \
} while (0)

// ---- W_j = (K^T)^j 1, j=1..3, per channel. 512 blocks x 256 thr ----
__global__ void __launch_bounds__(256) wj_kernel(const float* __restrict__ dwk,
                                                 float* __restrict__ W) {
    __shared__ float tA[30 * TS], tB[30 * TS];
    __shared__ float s_w[9];
    int c = blockIdx.x, t = threadIdx.x;
    ZERO_HALO(tA); ZERO_HALO(tB);
    if (t < 9) s_w[t] = dwk[c * 9 + 8 - t];   // flipped: K^T
    int py = t / 7, px4 = t - py * 7;
    if (t < F4) {
        float* d = &tA[(py + 1) * TS + px4 * 4 + 1];
        d[0] = d[1] = d[2] = d[3] = 1.f;
    }
    __syncthreads();
    float w0=s_w[0],w1=s_w[1],w2=s_w[2],w3=s_w[3],w4=s_w[4],w5=s_w[5],w6=s_w[6],w7=s_w[7],w8=s_w[8];
    float* src = tA; float* dst = tB;
    for (int it = 1; it <= 3; ++it) {
        if (t < F4) {
            float y0, y1, y2, y3;
            STENCIL(src, py, px4, w0,w1,w2,w3,w4,w5,w6,w7,w8, y0,y1,y2,y3);
            float* d = &dst[(py + 1) * TS + px4 * 4 + 1];
            d[0]=y0; d[1]=y1; d[2]=y2; d[3]=y3;
            ((float4*)(W + ((size_t)(it - 1) * CC + c) * HW))[t] = make_float4(y0,y1,y2,y3);
        }
        __syncthreads();
        float* tmp = src; src = dst; dst = tmp;
    }
}

// ---- mu_j[p] = <x plane p, W_j[c]>/784, j=0..3. 8192 blocks x 4 waves ----
__global__ void __launch_bounds__(256) stats_kernel(const float* __restrict__ x,
                                                    const float* __restrict__ W,
                                                    float* __restrict__ mu) {
    int wave = threadIdx.x >> 6, lane = threadIdx.x & 63;
    int p = blockIdx.x * 4 + wave;
    int c = p & 511;
    const float4* xv = (const float4*)(x + (size_t)p * HW);
    const float4* w1 = (const float4*)(W + (size_t)c * HW);
    const float4* w2 = (const float4*)(W + ((size_t)CC + c) * HW);
    const float4* w3 = (const float4*)(W + ((size_t)2 * CC + c) * HW);
    float s0 = 0.f, s1 = 0.f, s2 = 0.f, s3 = 0.f;
    for (int j = lane; j < F4; j += 64) {
        float4 v = xv[j], a = w1[j], b = w2[j], d = w3[j];
        s0 += v.x + v.y + v.z + v.w;
        s1 += v.x*a.x + v.y*a.y + v.z*a.z + v.w*a.w;
        s2 += v.x*b.x + v.y*b.y + v.z*b.z + v.w*b.w;
        s3 += v.x*d.x + v.y*d.y + v.z*d.z + v.w*d.w;
    }
    #pragma unroll
    for (int off = 32; off > 0; off >>= 1) {
        s0 += __shfl_down(s0, off, 64);
        s1 += __shfl_down(s1, off, 64);
        s2 += __shfl_down(s2, off, 64);
        s3 += __shfl_down(s3, off, 64);
    }
    if (lane == 0) {
        mu[p]          = s0 * (1.f / 784.f);
        mu[NP + p]     = s1 * (1.f / 784.f);
        mu[2 * NP + p] = s2 * (1.f / 784.f);
        mu[3 * NP + p] = s3 * (1.f / 784.f);
    }
}

// ---- cell for layer k: coef evolve (A_{k-1}) + seq from mu + LSTM + hh tail ----
__global__ void __launch_bounds__(512) cell_kernel(
        const float* __restrict__ mu, float* __restrict__ coef,
        const float* __restrict__ w_ih1, const float* __restrict__ b_ih1,
        const float* __restrict__ w_ih2, const float* __restrict__ b_ih2,
        const float* __restrict__ w_hh1, const float* __restrict__ b_hh1,
        const float* __restrict__ w_hh2, const float* __restrict__ b_hh2,
        float* __restrict__ G_i, float* __restrict__ ct,
        float* __restrict__ g_hpre, float* __restrict__ g_h2c,
        float* __restrict__ ct0c, int k) {
    __shared__ __align__(16) float s_in[CC];
    __shared__ float s_hid[32];
    __shared__ float s_hid2[32];
    __shared__ float s_g[1536];
    const int b = blockIdx.x, t = threadIdx.x;   // t == channel c
    const int p = b * CC + t;

    // step 1: apply A_{k-1} = 1 + out_h_{k-1}[b,c] to the K-polynomial coeffs
    float c0, c1, c2, c3;
    if (k == 0) {
        c0 = 1.f; c1 = c2 = c3 = 0.f;
        if (t < 32) s_hid2[t] = fmaxf(b_hh1[t], 0.f);
    } else {
        c0 = coef[p]; c1 = coef[NP + p]; c2 = coef[2 * NP + p]; c3 = coef[3 * NP + p];
        const float* g  = G_i + b * 1536;
        const float* gh = g_h2c + (size_t)(k - 1) * 1536;
        float ig = g[t] + gh[t];
        float fg = g[CC + t] + gh[CC + t];
        float cg = g[2 * CC + t] + gh[2 * CC + t];
        float nc = sigm(fg) * ct0c[(k - 1) * CC + t] + sigm(ig) * tanhf(cg);
        float A = 1.f + sigm(nc);
        c3 = A * c3 + c2; c2 = A * c2 + c1; c1 = A * c1 + c0; c0 = A * c0;
    }
    coef[p] = c0; coef[NP + p] = c1; coef[2 * NP + p] = c2; coef[3 * NP + p] = c3;
    s_in[t] = c0 * mu[p] + c1 * mu[NP + p] + c2 * mu[2 * NP + p] + c3 * mu[3 * NP + p];
    __syncthreads();

    // A-ih: 32 outputs x 16 lanes, float4 MACs
    {
        int o = t >> 4, q = t & 15;
        const float4* wv4 = (const float4*)(w_ih1 + o * CC) + q * 8;
        const float4* in4 = (const float4*)s_in + q * 8;
        float acc = 0.f;
        #pragma unroll
        for (int j = 0; j < 8; ++j) {
            float4 w = wv4[j], xv = in4[j];
            acc += xv.x*w.x + xv.y*w.y + xv.z*w.z + xv.w*w.w;
        }
        acc += __shfl_down(acc, 8, 64);
        acc += __shfl_down(acc, 4, 64);
        acc += __shfl_down(acc, 2, 64);
        acc += __shfl_down(acc, 1, 64);
        if (q == 0) s_hid[o] = fmaxf(acc + b_ih1[o], 0.f);
    }
    __syncthreads();

    // B: G_i and s_g = G_i + g_h(prev ht). Layer 0: g_h inline from relu(b_hh1).
    for (int o = t; o < 1536; o += 512) {
        const float4* wv4 = (const float4*)(w_ih2 + o * 32);
        float acc = 0.f;
        #pragma unroll
        for (int j = 0; j < 8; ++j) {
            float4 w = wv4[j];
            acc += s_hid[4*j]*w.x + s_hid[4*j+1]*w.y + s_hid[4*j+2]*w.z + s_hid[4*j+3]*w.w;
        }
        float gi = acc + b_ih2[o];
        G_i[b * 1536 + o] = gi;
        float gh;
        if (k == 0) {
            const float4* hv4 = (const float4*)(w_hh2 + o * 32);
            float a2 = 0.f;
            #pragma unroll
            for (int j = 0; j < 8; ++j) {
                float4 w = hv4[j];
                a2 += s_hid2[4*j]*w.x + s_hid2[4*j+1]*w.y + s_hid2[4*j+2]*w.z + s_hid2[4*j+3]*w.w;
            }
            gh = a2 + b_hh2[o];
        } else {
            gh = g_hpre[b * 1536 + o];
        }
        s_g[o] = gi + gh;
    }
    __syncthreads();

    // C: gates -> ct, h
    {
        float ctold = (k == 0) ? 0.f : ct[p];
        float nc = sigm(s_g[CC + t]) * ctold + sigm(s_g[t]) * tanhf(s_g[2 * CC + t]);
        ct[p] = nc;
        if (b == 0) ct0c[k * CC + t] = nc;
        s_in[t] = sigm(nc);
    }
    __syncthreads();

    // A-hh on new h
    {
        int o = t >> 4, q = t & 15;
        const float4* wv4 = (const float4*)(w_hh1 + o * CC) + q * 8;
        const float4* in4 = (const float4*)s_in + q * 8;
        float acc = 0.f;
        #pragma unroll
        for (int j = 0; j < 8; ++j) {
            float4 w = wv4[j], xv = in4[j];
            acc += xv.x*w.x + xv.y*w.y + xv.z*w.z + xv.w*w.w;
        }
        acc += __shfl_down(acc, 8, 64);
        acc += __shfl_down(acc, 4, 64);
        acc += __shfl_down(acc, 2, 64);
        acc += __shfl_down(acc, 1, 64);
        if (q == 0) s_hid[o] = fmaxf(acc + b_hh1[o], 0.f);
    }
    __syncthreads();

    // B-hh -> g_hpre[b]; block 0 snapshots to g_h2c[k]
    for (int o = t; o < 1536; o += 512) {
        const float4* wv4 = (const float4*)(w_hh2 + o * 32);
        float acc = 0.f;
        #pragma unroll
        for (int j = 0; j < 8; ++j) {
            float4 w = wv4[j];
            acc += s_hid[4*j]*w.x + s_hid[4*j+1]*w.y + s_hid[4*j+2]*w.z + s_hid[4*j+3]*w.w;
        }
        acc += b_hh2[o];
        g_hpre[b * 1536 + o] = acc;
        if (b == 0) g_h2c[(size_t)k * 1536 + o] = acc;
    }
}

// ---- out = sum_{j=0..4} e_j K^j x0, one block per plane ----
__global__ void __launch_bounds__(256) mega_kernel(
        const float* __restrict__ x, float* __restrict__ out,
        const float* __restrict__ G_i, const float* __restrict__ g_h2c,
        const float* __restrict__ ct0c, const float* __restrict__ coef,
        const float* __restrict__ dwk) {
    __shared__ float tA[30 * TS], tB[30 * TS];
    __shared__ float s_w[9];
    __shared__ float s_e[5];
    int p = blockIdx.x, t = threadIdx.x;
    int b = p >> 9, c = p & 511;
    ZERO_HALO(tA); ZERO_HALO(tB);
    if (t < 9) s_w[t] = dwk[c * 9 + t];   // forward conv (cross-correlation)
    if (t == 255) {
        const float* g  = G_i + b * 1536;
        const float* gh = g_h2c + 3 * 1536;
        float ig = g[c] + gh[c];
        float fg = g[CC + c] + gh[CC + c];
        float cg = g[2 * CC + c] + gh[2 * CC + c];
        float nc = sigm(fg) * ct0c[3 * CC + c] + sigm(ig) * tanhf(cg);
        float A = 1.f + sigm(nc);
        float c0 = coef[p], c1 = coef[NP + p], c2 = coef[2 * NP + p], c3 = coef[3 * NP + p];
        s_e[4] = c3;
        s_e[3] = A * c3 + c2;
        s_e[2] = A * c2 + c1;
        s_e[1] = A * c1 + c0;
        s_e[0] = A * c0;
    }
    int py = t / 7, px4 = t - py * 7;
    float4 v = make_float4(0.f, 0.f, 0.f, 0.f);
    if (t < F4) {
        v = ((const float4*)(x + (size_t)p * HW))[t];
        float* d = &tA[(py + 1) * TS + px4 * 4 + 1];
        d[0] = v.x; d[1] = v.y; d[2] = v.z; d[3] = v.w;
    }
    __syncthreads();
    float w0=s_w[0],w1=s_w[1],w2=s_w[2],w3=s_w[3],w4=s_w[4],w5=s_w[5],w6=s_w[6],w7=s_w[7],w8=s_w[8];
    float e0=s_e[0], e1=s_e[1], e2=s_e[2], e3=s_e[3], e4=s_e[4];
    float acc0 = e0 * v.x, acc1 = e0 * v.y, acc2 = e0 * v.z, acc3 = e0 * v.w;
    float* src = tA; float* dst = tB;
    #pragma unroll
    for (int it = 1; it <= 4; ++it) {
        float e = (it == 1) ? e1 : (it == 2) ? e2 : (it == 3) ? e3 : e4;
        if (t < F4) {
            float y0, y1, y2, y3;
            STENCIL(src, py, px4, w0,w1,w2,w3,w4,w5,w6,w7,w8, y0,y1,y2,y3);
            acc0 += e * y0; acc1 += e * y1; acc2 += e * y2; acc3 += e * y3;
            float* d = &dst[(py + 1) * TS + px4 * 4 + 1];
            d[0]=y0; d[1]=y1; d[2]=y2; d[3]=y3;
        }
        __syncthreads();
        float* tmp = src; src = dst; dst = tmp;
    }
    if (t < F4)
        ((float4*)(out + (size_t)p * HW))[t] = make_float4(acc0, acc1, acc2, acc3);
}

extern "C" void kernel_launch(void* const* d_in, const int* in_sizes, int n_in,
                              void* d_out, int out_size, void* d_ws, size_t ws_size,
                              hipStream_t stream) {
    const float* x_in  = (const float*)d_in[0];
    const float* w_ih1 = (const float*)d_in[1];
    const float* b_ih1 = (const float*)d_in[2];
    const float* w_ih2 = (const float*)d_in[3];
    const float* b_ih2 = (const float*)d_in[4];
    const float* w_hh1 = (const float*)d_in[5];
    const float* b_hh1 = (const float*)d_in[6];
    const float* w_hh2 = (const float*)d_in[7];
    const float* b_hh2 = (const float*)d_in[8];
    const float* dwk   = (const float*)d_in[9];
    float* out = (float*)d_out;
    char* ws = (char*)d_ws;

    float* mu    = (float*)(ws + 0);         // 4*NP*4   = 524288 B
    float* coef  = (float*)(ws + 524288);    // 4*NP*4   = 524288 B
    float* G_i   = (float*)(ws + 1048576);   // 64*1536*4 = 393216 B
    float* ct    = (float*)(ws + 1441792);   // 64*512*4  = 131072 B
    float* g_hpre= (float*)(ws + 1572864);   // 64*1536*4 = 393216 B
    float* g_h2c = (float*)(ws + 1966080);   // 4*1536*4  = 24576 B
    float* ct0c  = (float*)(ws + 1990656);   // 4*512*4   = 8192 B
    float* Wbuf  = (float*)(ws + 1998848);   // 3*512*784*4 = 4816896 B

    wj_kernel<<<512, 256, 0, stream>>>(dwk, Wbuf);
    stats_kernel<<<8192, 256, 0, stream>>>(x_in, Wbuf, mu);
    for (int k = 0; k < 4; ++k)
        cell_kernel<<<BB, 512, 0, stream>>>(mu, coef, w_ih1, b_ih1, w_ih2, b_ih2,
                                            w_hh1, b_hh1, w_hh2, b_hh2,
                                            G_i, ct, g_hpre, g_h2c, ct0c, k);
    mega_kernel<<<NP, 256, 0, stream>>>(x_in, out, G_i, g_h2c, ct0c, coef, dwk);
}

// Round 4
// 337.517 us; speedup vs baseline: 1.3641x; 1.1107x over previous
//
#include <hip/hip_runtime.h>

// B=64, C=512, H=W=28, NL=4, fp32. Layer update is LINEAR per plane:
// x_4 = sum_{j=0..4} e_j K^j x_0 (K = zero-padded depthwise 3x3), e from cells.
// mega v2: column-in-register Horner stencil, 2 planes/wave, LDS only for
// left/right column exchange (7x ds_read_b128, odd f4-stride 9 -> conflict-free).

#define HW 784
#define F4 196
#define CC 512
#define BB 64
#define NP 32768
#define TS 31

__device__ __forceinline__ float sigm(float x) { return 1.f / (1.f + __expf(-x)); }

// 3x3 stencil on a 30x31 padded tile (wj_kernel only)
#define STENCIL(src, py, px4, w0,w1,w2,w3,w4,w5,w6,w7,w8, y0,y1,y2,y3) do { \
    const float* r0 = &(src)[(py) * TS + (px4) * 4]; \
    const float* r1 = r0 + TS; \
    const float* r2 = r0 + 2 * TS; \
    float a0=r0[0],a1=r0[1],a2=r0[2],a3=r0[3],a4=r0[4],a5=r0[5]; \
    float b0=r1[0],b1=r1[1],b2=r1[2],b3=r1[3],b4=r1[4],b5=r1[5]; \
    float c0=r2[0],c1=r2[1],c2=r2[2],c3=r2[3],c4=r2[4],c5=r2[5]; \
    y0 = a0*w0+a1*w1+a2*w2 + b0*w3+b1*w4+b2*w5 + c0*w6+c1*w7+c2*w8; \
    y1 = a1*w0+a2*w1+a3*w2 + b1*w3+b2*w4+b3*w5 + c1*w6+c2*w7+c3*w8; \
    y2 = a2*w0+a3*w1+a4*w2 + b2*w3+b3*w4+b4*w5 + c2*w6+c3*w7+c4*w8; \
    y3 = a3*w0+a4*w1+a5*w2 + b3*w3+b4*w4+b5*w5 + c3*w6+c4*w7+c5*w8; \
} while (0)

#define ZERO_HALO(tile) do { \
    if (t < 30) (tile)[t] = 0.f; \
    else if (t < 60) (tile)[29 * TS + (t - 30)] = 0.f; \
    else if (t < 88) (tile)[(t - 59) * TS] = 0.f; \
    else if (t < 116) (tile)[(t - 87) * TS + 29] = 0.f; \
} while (0)

// ---- W_j = (K^T)^j 1, j=1..3, per channel ----
__global__ void __launch_bounds__(256) wj_kernel(const float* __restrict__ dwk,
                                                 float* __restrict__ W) {
    __shared__ float tA[30 * TS], tB[30 * TS];
    __shared__ float s_w[9];
    int c = blockIdx.x, t = threadIdx.x;
    ZERO_HALO(tA); ZERO_HALO(tB);
    if (t < 9) s_w[t] = dwk[c * 9 + 8 - t];   // flipped: K^T
    int py = t / 7, px4 = t - py * 7;
    if (t < F4) {
        float* d = &tA[(py + 1) * TS + px4 * 4 + 1];
        d[0] = d[1] = d[2] = d[3] = 1.f;
    }
    __syncthreads();
    float w0=s_w[0],w1=s_w[1],w2=s_w[2],w3=s_w[3],w4=s_w[4],w5=s_w[5],w6=s_w[6],w7=s_w[7],w8=s_w[8];
    float* src = tA; float* dst = tB;
    for (int it = 1; it <= 3; ++it) {
        if (t < F4) {
            float y0, y1, y2, y3;
            STENCIL(src, py, px4, w0,w1,w2,w3,w4,w5,w6,w7,w8, y0,y1,y2,y3);
            float* d = &dst[(py + 1) * TS + px4 * 4 + 1];
            d[0]=y0; d[1]=y1; d[2]=y2; d[3]=y3;
            ((float4*)(W + ((size_t)(it - 1) * CC + c) * HW))[t] = make_float4(y0,y1,y2,y3);
        }
        __syncthreads();
        float* tmp = src; src = dst; dst = tmp;
    }
}

// ---- mu_j[p] = <x plane p, W_j[c]>/784, j=0..3 ----
__global__ void __launch_bounds__(256) stats_kernel(const float* __restrict__ x,
                                                    const float* __restrict__ W,
                                                    float* __restrict__ mu) {
    int wave = threadIdx.x >> 6, lane = threadIdx.x & 63;
    int p = blockIdx.x * 4 + wave;
    int c = p & 511;
    const float4* xv = (const float4*)(x + (size_t)p * HW);
    const float4* w1 = (const float4*)(W + (size_t)c * HW);
    const float4* w2 = (const float4*)(W + ((size_t)CC + c) * HW);
    const float4* w3 = (const float4*)(W + ((size_t)2 * CC + c) * HW);
    float s0 = 0.f, s1 = 0.f, s2 = 0.f, s3 = 0.f;
    for (int j = lane; j < F4; j += 64) {
        float4 v = xv[j], a = w1[j], b = w2[j], d = w3[j];
        s0 += v.x + v.y + v.z + v.w;
        s1 += v.x*a.x + v.y*a.y + v.z*a.z + v.w*a.w;
        s2 += v.x*b.x + v.y*b.y + v.z*b.z + v.w*b.w;
        s3 += v.x*d.x + v.y*d.y + v.z*d.z + v.w*d.w;
    }
    #pragma unroll
    for (int off = 32; off > 0; off >>= 1) {
        s0 += __shfl_down(s0, off, 64);
        s1 += __shfl_down(s1, off, 64);
        s2 += __shfl_down(s2, off, 64);
        s3 += __shfl_down(s3, off, 64);
    }
    if (lane == 0) {
        mu[p]          = s0 * (1.f / 784.f);
        mu[NP + p]     = s1 * (1.f / 784.f);
        mu[2 * NP + p] = s2 * (1.f / 784.f);
        mu[3 * NP + p] = s3 * (1.f / 784.f);
    }
}

// ---- cell for layer k ----
__global__ void __launch_bounds__(512) cell_kernel(
        const float* __restrict__ mu, float* __restrict__ coef,
        const float* __restrict__ w_ih1, const float* __restrict__ b_ih1,
        const float* __restrict__ w_ih2, const float* __restrict__ b_ih2,
        const float* __restrict__ w_hh1, const float* __restrict__ b_hh1,
        const float* __restrict__ w_hh2, const float* __restrict__ b_hh2,
        float* __restrict__ G_i, float* __restrict__ ct,
        float* __restrict__ g_hpre, float* __restrict__ g_h2c,
        float* __restrict__ ct0c, int k) {
    __shared__ __align__(16) float s_in[CC];
    __shared__ float s_hid[32];
    __shared__ float s_hid2[32];
    __shared__ float s_g[1536];
    const int b = blockIdx.x, t = threadIdx.x;
    const int p = b * CC + t;

    float c0, c1, c2, c3;
    if (k == 0) {
        c0 = 1.f; c1 = c2 = c3 = 0.f;
        if (t < 32) s_hid2[t] = fmaxf(b_hh1[t], 0.f);
    } else {
        c0 = coef[p]; c1 = coef[NP + p]; c2 = coef[2 * NP + p]; c3 = coef[3 * NP + p];
        const float* g  = G_i + b * 1536;
        const float* gh = g_h2c + (size_t)(k - 1) * 1536;
        float ig = g[t] + gh[t];
        float fg = g[CC + t] + gh[CC + t];
        float cg = g[2 * CC + t] + gh[2 * CC + t];
        float nc = sigm(fg) * ct0c[(k - 1) * CC + t] + sigm(ig) * tanhf(cg);
        float A = 1.f + sigm(nc);
        c3 = A * c3 + c2; c2 = A * c2 + c1; c1 = A * c1 + c0; c0 = A * c0;
    }
    coef[p] = c0; coef[NP + p] = c1; coef[2 * NP + p] = c2; coef[3 * NP + p] = c3;
    s_in[t] = c0 * mu[p] + c1 * mu[NP + p] + c2 * mu[2 * NP + p] + c3 * mu[3 * NP + p];
    __syncthreads();

    {
        int o = t >> 4, q = t & 15;
        const float4* wv4 = (const float4*)(w_ih1 + o * CC) + q * 8;
        const float4* in4 = (const float4*)s_in + q * 8;
        float acc = 0.f;
        #pragma unroll
        for (int j = 0; j < 8; ++j) {
            float4 w = wv4[j], xv = in4[j];
            acc += xv.x*w.x + xv.y*w.y + xv.z*w.z + xv.w*w.w;
        }
        acc += __shfl_down(acc, 8, 64);
        acc += __shfl_down(acc, 4, 64);
        acc += __shfl_down(acc, 2, 64);
        acc += __shfl_down(acc, 1, 64);
        if (q == 0) s_hid[o] = fmaxf(acc + b_ih1[o], 0.f);
    }
    __syncthreads();

    for (int o = t; o < 1536; o += 512) {
        const float4* wv4 = (const float4*)(w_ih2 + o * 32);
        float acc = 0.f;
        #pragma unroll
        for (int j = 0; j < 8; ++j) {
            float4 w = wv4[j];
            acc += s_hid[4*j]*w.x + s_hid[4*j+1]*w.y + s_hid[4*j+2]*w.z + s_hid[4*j+3]*w.w;
        }
        float gi = acc + b_ih2[o];
        G_i[b * 1536 + o] = gi;
        float gh;
        if (k == 0) {
            const float4* hv4 = (const float4*)(w_hh2 + o * 32);
            float a2 = 0.f;
            #pragma unroll
            for (int j = 0; j < 8; ++j) {
                float4 w = hv4[j];
                a2 += s_hid2[4*j]*w.x + s_hid2[4*j+1]*w.y + s_hid2[4*j+2]*w.z + s_hid2[4*j+3]*w.w;
            }
            gh = a2 + b_hh2[o];
        } else {
            gh = g_hpre[b * 1536 + o];
        }
        s_g[o] = gi + gh;
    }
    __syncthreads();

    {
        float ctold = (k == 0) ? 0.f : ct[p];
        float nc = sigm(s_g[CC + t]) * ctold + sigm(s_g[t]) * tanhf(s_g[2 * CC + t]);
        ct[p] = nc;
        if (b == 0) ct0c[k * CC + t] = nc;
        s_in[t] = sigm(nc);
    }
    __syncthreads();

    {
        int o = t >> 4, q = t & 15;
        const float4* wv4 = (const float4*)(w_hh1 + o * CC) + q * 8;
        const float4* in4 = (const float4*)s_in + q * 8;
        float acc = 0.f;
        #pragma unroll
        for (int j = 0; j < 8; ++j) {
            float4 w = wv4[j], xv = in4[j];
            acc += xv.x*w.x + xv.y*w.y + xv.z*w.z + xv.w*w.w;
        }
        acc += __shfl_down(acc, 8, 64);
        acc += __shfl_down(acc, 4, 64);
        acc += __shfl_down(acc, 2, 64);
        acc += __shfl_down(acc, 1, 64);
        if (q == 0) s_hid[o] = fmaxf(acc + b_hh1[o], 0.f);
    }
    __syncthreads();

    for (int o = t; o < 1536; o += 512) {
        const float4* wv4 = (const float4*)(w_hh2 + o * 32);
        float acc = 0.f;
        #pragma unroll
        for (int j = 0; j < 8; ++j) {
            float4 w = wv4[j];
            acc += s_hid[4*j]*w.x + s_hid[4*j+1]*w.y + s_hid[4*j+2]*w.z + s_hid[4*j+3]*w.w;
        }
        acc += b_hh2[o];
        g_hpre[b * 1536 + o] = acc;
        if (b == 0) g_h2c[(size_t)k * 1536 + o] = acc;
    }
}

// ---- mega v2 helpers ----
__device__ __forceinline__ void rdcol(const float4* C4, int cc, float (&D)[28]) {
    const float4* s4 = C4 + cc * 9;
    #pragma unroll
    for (int j = 0; j < 7; ++j) {
        float4 v = s4[j];
        D[4*j] = v.x; D[4*j+1] = v.y; D[4*j+2] = v.z; D[4*j+3] = v.w;
    }
}
__device__ __forceinline__ void zcol(float (&D)[28]) {
    #pragma unroll
    for (int r = 0; r < 28; ++r) D[r] = 0.f;
}
__device__ __forceinline__ void wrcol(float4* C4, int cc, const float (&S)[28]) {
    #pragma unroll
    for (int j = 0; j < 7; ++j)
        C4[cc * 9 + j] = make_float4(S[4*j], S[4*j+1], S[4*j+2], S[4*j+3]);
}

// ---- mega: out = sum_j e_j K^j x0 via Horner; column registers, 2 planes/wave ----
__global__ void __launch_bounds__(256) mega_kernel(
        const float* __restrict__ x, float* __restrict__ out,
        const float* __restrict__ G_i, const float* __restrict__ g_h2c,
        const float* __restrict__ ct0c, const float* __restrict__ coef,
        const float* __restrict__ dwk) {
    __shared__ float lds[8 * 1008];   // per plane: 1008 floats (row-major 784 / col-major 28x9 f4)
    const int t = threadIdx.x;
    const int w = t >> 6, lane = t & 63;
    const int h = lane >> 5, c = lane & 31;
    const int pl = 2 * w + h;
    const int p = blockIdx.x * 8 + pl;
    const int b = p >> 9, ch = p & 511;
    const bool act = (c < 28);

    // stage wave's 2 planes: global f4 -> LDS row-major (stride 28 floats / 7 f4)
    {
        const float4* xg = (const float4*)(x + (size_t)(blockIdx.x * 8 + 2 * w) * HW);
        float4* L = (float4*)(lds + 2 * w * 1008);
        #pragma unroll
        for (int i0 = 0; i0 < 7; ++i0) {
            int i = i0 * 64 + lane;
            if (i < 392) {
                int q = i / 196, rem = i - q * 196;
                int row = rem / 7, c4 = rem - row * 7;
                L[q * 252 + row * 7 + c4] = xg[i];
            }
        }
    }
    asm volatile("" ::: "memory");

    // per-lane e coefficients (plane-uniform)
    const float* g  = G_i + b * 1536;
    const float* gh = g_h2c + 3 * 1536;
    float ig = g[ch] + gh[ch];
    float fg = g[CC + ch] + gh[CC + ch];
    float cg = g[2 * CC + ch] + gh[2 * CC + ch];
    float ncv = sigm(fg) * ct0c[3 * CC + ch] + sigm(ig) * tanhf(cg);
    float A = 1.f + sigm(ncv);
    float k0 = coef[p], k1 = coef[NP + p], k2 = coef[2 * NP + p], k3 = coef[3 * NP + p];
    float e4 = k3, e3 = A*k3 + k2, e2 = A*k2 + k1, e1 = A*k1 + k0, e0 = A*k0;
    float w0 = dwk[ch*9+0], w1 = dwk[ch*9+1], w2 = dwk[ch*9+2];
    float w3 = dwk[ch*9+3], w4 = dwk[ch*9+4], w5 = dwk[ch*9+5];
    float w6 = dwk[ch*9+6], w7 = dwk[ch*9+7], w8 = dwk[ch*9+8];

    float* P = lds + pl * 1008;
    float4* C4 = (float4*)lds + pl * 252;

    float xr[28], tt[28], l[28], rr[28];

    // own column x from row-major
    if (act) {
        #pragma unroll
        for (int r = 0; r < 28; ++r) xr[r] = P[r * 28 + c];
    }
    asm volatile("" ::: "memory");
    // write own column col-major (odd f4 stride 9 -> bank-spread)
    if (act) wrcol(C4, c, xr);
    asm volatile("" ::: "memory");

    // iter 1: tt = e3*x + e4*K(x)
    if (act) {
        if (c > 0) rdcol(C4, c - 1, l); else zcol(l);
        if (c < 27) rdcol(C4, c + 1, rr); else zcol(rr);
        #pragma unroll
        for (int r = 0; r < 28; ++r) {
            float tm1 = (r > 0) ? xr[r-1] : 0.f, tp1 = (r < 27) ? xr[r+1] : 0.f;
            float lm1 = (r > 0) ? l[r-1]  : 0.f, lp1 = (r < 27) ? l[r+1]  : 0.f;
            float rm1 = (r > 0) ? rr[r-1] : 0.f, rp1 = (r < 27) ? rr[r+1] : 0.f;
            float tap = w0*lm1 + w1*tm1 + w2*rm1 + w3*l[r] + w4*xr[r] + w5*rr[r]
                      + w6*lp1 + w7*tp1 + w8*rp1;
            tt[r] = e3 * xr[r] + e4 * tap;
        }
    }
    asm volatile("" ::: "memory");
    if (act) wrcol(C4, c, tt);
    asm volatile("" ::: "memory");

    // iters 2..4: tt = e*x + K(t_prev); in-place center column via pm1 carry
    #pragma unroll
    for (int it = 2; it <= 4; ++it) {
        float e = (it == 2) ? e2 : (it == 3) ? e1 : e0;
        if (act) {
            if (c > 0) rdcol(C4, c - 1, l); else zcol(l);
            if (c < 27) rdcol(C4, c + 1, rr); else zcol(rr);
            float pm1 = 0.f;
            #pragma unroll
            for (int r = 0; r < 28; ++r) {
                float cur = tt[r];
                float tp1 = (r < 27) ? tt[r+1] : 0.f;
                float lm1 = (r > 0) ? l[r-1]  : 0.f, lp1 = (r < 27) ? l[r+1]  : 0.f;
                float rm1 = (r > 0) ? rr[r-1] : 0.f, rp1 = (r < 27) ? rr[r+1] : 0.f;
                float tap = w0*lm1 + w1*pm1 + w2*rm1 + w3*l[r] + w4*cur + w5*rr[r]
                          + w6*lp1 + w7*tp1 + w8*rp1;
                tt[r] = e * xr[r] + tap;
                pm1 = cur;
            }
        }
        asm volatile("" ::: "memory");
        if (it < 4) {
            if (act) wrcol(C4, c, tt);
            asm volatile("" ::: "memory");
        }
    }

    // epilogue: out column -> row-major LDS -> coalesced global f4
    if (act) {
        #pragma unroll
        for (int r = 0; r < 28; ++r) P[r * 28 + c] = tt[r];
    }
    asm volatile("" ::: "memory");
    {
        float4* og = (float4*)(out + (size_t)(blockIdx.x * 8 + 2 * w) * HW);
        const float4* L = (const float4*)(lds + 2 * w * 1008);
        #pragma unroll
        for (int i0 = 0; i0 < 7; ++i0) {
            int i = i0 * 64 + lane;
            if (i < 392) {
                int q = i / 196, rem = i - q * 196;
                int row = rem / 7, c4 = rem - row * 7;
                og[i] = L[q * 252 + row * 7 + c4];
            }
        }
    }
}

extern "C" void kernel_launch(void* const* d_in, const int* in_sizes, int n_in,
                              void* d_out, int out_size, void* d_ws, size_t ws_size,
                              hipStream_t stream) {
    const float* x_in  = (const float*)d_in[0];
    const float* w_ih1 = (const float*)d_in[1];
    const float* b_ih1 = (const float*)d_in[2];
    const float* w_ih2 = (const float*)d_in[3];
    const float* b_ih2 = (const float*)d_in[4];
    const float* w_hh1 = (const float*)d_in[5];
    const float* b_hh1 = (const float*)d_in[6];
    const float* w_hh2 = (const float*)d_in[7];
    const float* b_hh2 = (const float*)d_in[8];
    const float* dwk   = (const float*)d_in[9];
    float* out = (float*)d_out;
    char* ws = (char*)d_ws;

    float* mu    = (float*)(ws + 0);         // 524288 B
    float* coef  = (float*)(ws + 524288);    // 524288 B
    float* G_i   = (float*)(ws + 1048576);   // 393216 B
    float* ct    = (float*)(ws + 1441792);   // 131072 B
    float* g_hpre= (float*)(ws + 1572864);   // 393216 B
    float* g_h2c = (float*)(ws + 1966080);   // 24576 B
    float* ct0c  = (float*)(ws + 1990656);   // 8192 B
    float* Wbuf  = (float*)(ws + 1998848);   // 4816896 B

    wj_kernel<<<512, 256, 0, stream>>>(dwk, Wbuf);
    stats_kernel<<<8192, 256, 0, stream>>>(x_in, Wbuf, mu);
    for (int k = 0; k < 4; ++k)
        cell_kernel<<<BB, 512, 0, stream>>>(mu, coef, w_ih1, b_ih1, w_ih2, b_ih2,
                                            w_hh1, b_hh1, w_hh2, b_hh2,
                                            G_i, ct, g_hpre, g_h2c, ct0c, k);
    mega_kernel<<<4096, 256, 0, stream>>>(x_in, out, G_i, g_h2c, ct0c, coef, dwk);
}